// Round 1
// baseline (256.573 us; speedup 1.0000x reference)
//
#include <hip/hip_runtime.h>
#include <math.h>

// Problem constants (reference: T,B,E,H = 1024,4,1024,16; DH=64; 32 buckets, max_dist 128)
#define T_ 1024
#define B_ 4
#define E_ 1024
#define H_ 16
#define DH_ 64

typedef __attribute__((ext_vector_type(8))) __bf16 bf16x8;
typedef __attribute__((ext_vector_type(4))) __bf16 bf16x4;
typedef __attribute__((ext_vector_type(4))) float f32x4;

// fp32 -> bf16 round-to-nearest-even (bit manipulation; no __hip_bfloat16 ABI dependence)
__device__ __forceinline__ __bf16 f2bf(float x){
  union { unsigned short u; __bf16 b; } cv;
  unsigned u32 = __float_as_uint(x);
  cv.u = (unsigned short)((u32 + 0x7fffu + ((u32 >> 16) & 1u)) >> 16);
  return cv.b;
}

// async global->LDS, 16B per lane; LDS dest is wave-uniform base + lane*16 (guide §5, m97/m104)
__device__ __forceinline__ void glds16(const void* g, void* l){
  __builtin_amdgcn_global_load_lds(
      (__attribute__((address_space(1))) void*)(void*)g,
      (__attribute__((address_space(3))) void*)l,
      16, 0, 0);
}

// ---------------- fp32 -> bf16 conversion (vectorized) ----------------
__global__ void cvt_bf16_kernel(const float* __restrict__ in, __bf16* __restrict__ out, int n){
  int i = (blockIdx.x * 256 + threadIdx.x) * 4;
  if (i >= n) return;
  float4 v = *(const float4*)(in + i);
  bf16x4 o;
  o[0] = f2bf(v.x); o[1] = f2bf(v.y); o[2] = f2bf(v.z); o[3] = f2bf(v.w);
  *(bf16x4*)(out + i) = o;
}

// ---------------- gates: g = sigmoid(groupsum(qh_raw . grep_w + grep_b)); gate=(sa*(sb*ga-1)+2) ----------------
__global__ void gates_kernel(const float* __restrict__ query, const float* __restrict__ gw,
                             const float* __restrict__ gb, const float* __restrict__ ga,
                             float* __restrict__ gates){
  int idx = blockIdx.x * 256 + threadIdx.x;     // idx = bh*1024 + t
  int t = idx & (T_ - 1);
  int bh = idx >> 10;
  int b = bh >> 4, h = bh & 15;
  const float* q = query + (size_t)t * (B_ * E_) + b * E_ + h * DH_;  // qh_raw[b,h,t,:]
  float g[8];
  #pragma unroll
  for (int e = 0; e < 8; e++) g[e] = gb[e];
  for (int d = 0; d < DH_; d++){
    float qd = q[d];
    #pragma unroll
    for (int e = 0; e < 8; e++) g[e] += qd * gw[e * DH_ + d];   // gw uniform -> s_load
  }
  float a0 = (g[0] + g[1]) + (g[2] + g[3]);
  float a1 = (g[4] + g[5]) + (g[6] + g[7]);
  float sa = 1.f / (1.f + __expf(-a0));
  float sb = 1.f / (1.f + __expf(-a1));
  gates[idx] = sa * (sb * ga[h] - 1.0f) + 2.0f;
}

// ---------------- relative-position bias table: tab[h][rp+1023] = rel_bias[bucket(rp), h] ----------------
__global__ void tab_kernel(const float* __restrict__ rel_bias, float* __restrict__ tab){
  int i = blockIdx.x * 256 + threadIdx.x;
  if (i >= 2047) return;
  int h = blockIdx.y;
  int rp = i - 1023;                 // rp = s - t
  int base = rp > 0 ? 16 : 0;        // n = NUM_BUCKETS/2 = 16
  int arp = rp < 0 ? -rp : rp;
  int off;
  if (arp < 8) off = arp;            // max_exact = 8
  else {
    // mimic reference f32 math: log(arp/8)/log(16)*8, trunc toward 0, clamp 15
    float val = (logf((float)arp * 0.125f) / 2.772588722239781f) * 8.0f;
    int lg = (int)val;
    off = 8 + (lg > 7 ? 7 : lg);
  }
  tab[h * 2047 + i] = rel_bias[(base + off) * H_ + h];
}

// ---------------- bf16 MFMA GEMM: C[m,n] = (sum_k A[m,k]*W[n,k] + bias[n]) * scale ----------------
// 128x128 tile, BK=32, 256 thr (4 waves, 2x2 of 64x64), m97-style global_load_lds staging.
// MODE 0: z in {0,1,2} selects q(scale=.125)/k/v weights; scatter-write bf16 to (B,H,T,DH).
// MODE 1: plain fp32 row-major write (final out-proj).
template<int MODE>
__global__ __launch_bounds__(256) void gemm_kernel(
    const __bf16* __restrict__ A,
    const __bf16* __restrict__ W0, const __bf16* __restrict__ W1, const __bf16* __restrict__ W2,
    const float* __restrict__ b0, const float* __restrict__ b1, const float* __restrict__ b2,
    void* out0, void* out1, void* out2)
{
  __shared__ __bf16 As[128 * 32];   // unpadded: required by global_load_lds; frag reads are phase-minimal
  __shared__ __bf16 Bs[128 * 32];
  const int tid = threadIdx.x;
  const int lane = tid & 63, wid = tid >> 6;
  const int l15 = lane & 15, quad = lane >> 4;
  const int wm = wid >> 1, wn = wid & 1;
  const int m0 = blockIdx.y * 128, n0 = blockIdx.x * 128;

  const __bf16* W = W0;
  const float* bias = b0;
  float scale = 1.0f;
  void* outp = out0;
  if (MODE == 0){
    int z = blockIdx.z;
    if (z == 0){ scale = 0.125f; }                       // q: *DH^-0.5
    else if (z == 1){ W = W1; bias = b1; outp = out1; }  // k
    else            { W = W2; bias = b2; outp = out2; }  // v
  }

  f32x4 acc[4][4];
  #pragma unroll
  for (int i = 0; i < 4; i++)
    #pragma unroll
    for (int j = 0; j < 4; j++){
      acc[i][j][0] = 0.f; acc[i][j][1] = 0.f; acc[i][j][2] = 0.f; acc[i][j][3] = 0.f;
    }

  const int grow = lane >> 2;          // 16 rows per wave-load round
  const int gcol = (lane & 3) * 8;     // 4 x 16B chunks per row

  for (int k0 = 0; k0 < E_; k0 += 32){
    __syncthreads();
    #pragma unroll
    for (int r2 = 0; r2 < 2; r2++){
      int rb = (wid * 2 + r2) * 16;    // wave-uniform row-group base
      glds16(A + (size_t)(m0 + rb + grow) * E_ + k0 + gcol, &As[rb * 32]);
      glds16(W + (size_t)(n0 + rb + grow) * E_ + k0 + gcol, &Bs[rb * 32]);
    }
    __syncthreads();                   // barrier drains vmcnt -> staged data visible
    bf16x8 am[4], bn[4];
    #pragma unroll
    for (int i = 0; i < 4; i++) am[i] = *(const bf16x8*)&As[(wm * 64 + i * 16 + l15) * 32 + quad * 8];
    #pragma unroll
    for (int j = 0; j < 4; j++) bn[j] = *(const bf16x8*)&Bs[(wn * 64 + j * 16 + l15) * 32 + quad * 8];
    #pragma unroll
    for (int i = 0; i < 4; i++)
      #pragma unroll
      for (int j = 0; j < 4; j++)
        acc[i][j] = __builtin_amdgcn_mfma_f32_16x16x32_bf16(am[i], bn[j], acc[i][j], 0, 0, 0);
  }

  // epilogue: C/D layout col=lane&15, row=quad*4+reg (measured m89/m91)
  #pragma unroll
  for (int i = 0; i < 4; i++){
    const int row0 = m0 + wm * 64 + i * 16 + quad * 4;
    #pragma unroll
    for (int j = 0; j < 4; j++){
      const int col = n0 + wn * 64 + j * 16 + l15;
      const float bc = bias[col];
      #pragma unroll
      for (int r = 0; r < 4; r++){
        float v = (acc[i][j][r] + bc) * scale;
        int row = row0 + r;
        if (MODE == 0){
          int t = row >> 2, bb = row & 3;       // m = t*B + b
          int hh = col >> 6, d = col & 63;      // n = h*DH + d
          ((__bf16*)outp)[(size_t)((bb * H_ + hh) * T_ + t) * DH_ + d] = f2bf(v);
        } else {
          ((float*)outp)[(size_t)row * E_ + col] = v;
        }
      }
    }
  }
}

// ---------------- flash attention, bf16 MFMA 16x16x32, online softmax ----------------
// grid (T/64, B*H); block 256 = 4 waves; wave owns 16 q-rows; s-tiles of 64.
__global__ __launch_bounds__(256) void attn_kernel(
    const __bf16* __restrict__ qg, const __bf16* __restrict__ kg, const __bf16* __restrict__ vg,
    const float* __restrict__ gates, const float* __restrict__ tab,
    __bf16* __restrict__ ctx)
{
  const int LD = 72;                 // 144B row stride: 16B-aligned, b128 frag reads phase-minimal
  __shared__ __bf16 Ks[64 * 72];     // K-tile (s, d)
  __shared__ __bf16 Vt[64 * 72];     // V-tile transposed (d, s) -> PV B-frags contiguous
  __shared__ __bf16 Pw[4][16 * 72];  // per-wave P round-trip buffer
  __shared__ float tabh[2048];       // rel-bias row for this h, indexed by rp+1023

  const int tid = threadIdx.x;
  const int lane = tid & 63, wid = tid >> 6;
  const int l15 = lane & 15, quad = lane >> 4;
  const int bh = blockIdx.y;
  const int b = bh >> 4, h = bh & 15;
  const __bf16* qb = qg + (size_t)bh * T_ * DH_;
  const __bf16* kb = kg + (size_t)bh * T_ * DH_;
  const __bf16* vb = vg + (size_t)bh * T_ * DH_;

  for (int i = tid; i < 2047; i += 256) tabh[i] = tab[h * 2047 + i];

  const int t0 = blockIdx.x * 64 + wid * 16;
  // Q A-frags direct from global: A[m=lane&15][k=quad*8+j] (measured m120); fixed across s-loop
  bf16x8 aq0 = *(const bf16x8*)(qb + (size_t)(t0 + l15) * DH_ + quad * 8);
  bf16x8 aq1 = *(const bf16x8*)(qb + (size_t)(t0 + l15) * DH_ + 32 + quad * 8);
  float g4[4];
  #pragma unroll
  for (int r = 0; r < 4; r++) g4[r] = gates[bh * T_ + t0 + quad * 4 + r];

  float m_run[4], l_run[4];
  f32x4 O[4];
  #pragma unroll
  for (int r = 0; r < 4; r++){ m_run[r] = -INFINITY; l_run[r] = 0.f; }
  #pragma unroll
  for (int dt = 0; dt < 4; dt++){ O[dt][0] = 0.f; O[dt][1] = 0.f; O[dt][2] = 0.f; O[dt][3] = 0.f; }

  for (int s0 = 0; s0 < T_; s0 += 64){
    __syncthreads();   // protect LDS restage vs previous iter reads (also makes tabh visible, iter 0)
    #pragma unroll
    for (int r2 = 0; r2 < 2; r2++){
      int cid = r2 * 256 + tid;                      // K: 512 x 16B chunks
      int srow = cid >> 3, c = cid & 7;
      bf16x8 kvv = *(const bf16x8*)(kb + (size_t)(s0 + srow) * DH_ + c * 8);
      *(bf16x8*)&Ks[srow * LD + c * 8] = kvv;
      int sv = tid & 63, d0 = (tid >> 6) * 16 + r2 * 8;  // V: load row chunk, scatter transposed
      bf16x8 vv = *(const bf16x8*)(vb + (size_t)(s0 + sv) * DH_ + d0);
      #pragma unroll
      for (int q2 = 0; q2 < 8; q2++) Vt[(d0 + q2) * LD + sv] = vv[q2];
    }
    __syncthreads();

    // S = Q.K^T  (B-frag: n=lane&15 over s-cols, k=quad*8+j over d)
    f32x4 S[4];
    #pragma unroll
    for (int nt = 0; nt < 4; nt++){
      bf16x8 bk0 = *(const bf16x8*)&Ks[(nt * 16 + l15) * LD + quad * 8];
      bf16x8 bk1 = *(const bf16x8*)&Ks[(nt * 16 + l15) * LD + 32 + quad * 8];
      f32x4 a; a[0] = 0.f; a[1] = 0.f; a[2] = 0.f; a[3] = 0.f;
      a = __builtin_amdgcn_mfma_f32_16x16x32_bf16(aq0, bk0, a, 0, 0, 0);
      a = __builtin_amdgcn_mfma_f32_16x16x32_bf16(aq1, bk1, a, 0, 0, 0);
      S[nt] = a;
    }
    // + attn_bias = gate(b,h,t) * rel_bias[bucket(s-t), h]
    #pragma unroll
    for (int nt = 0; nt < 4; nt++)
      #pragma unroll
      for (int r = 0; r < 4; r++){
        int t = t0 + quad * 4 + r;
        int s = s0 + nt * 16 + l15;
        S[nt][r] += g4[r] * tabh[s - t + 1023];
      }

    // online softmax: row stats across 16 lanes of each quad (masks 1,2,4,8 stay in-quad)
    float mx[4];
    #pragma unroll
    for (int r = 0; r < 4; r++) mx[r] = fmaxf(fmaxf(S[0][r], S[1][r]), fmaxf(S[2][r], S[3][r]));
    #pragma unroll
    for (int off = 1; off < 16; off <<= 1)
      #pragma unroll
      for (int r = 0; r < 4; r++) mx[r] = fmaxf(mx[r], __shfl_xor(mx[r], off, 64));
    float al[4];
    #pragma unroll
    for (int r = 0; r < 4; r++){
      float mn = fmaxf(m_run[r], mx[r]);
      al[r] = __expf(m_run[r] - mn);
      m_run[r] = mn;
    }
    #pragma unroll
    for (int nt = 0; nt < 4; nt++)
      #pragma unroll
      for (int r = 0; r < 4; r++) S[nt][r] = __expf(S[nt][r] - m_run[r]);
    float rs[4];
    #pragma unroll
    for (int r = 0; r < 4; r++) rs[r] = (S[0][r] + S[1][r]) + (S[2][r] + S[3][r]);
    #pragma unroll
    for (int off = 1; off < 16; off <<= 1)
      #pragma unroll
      for (int r = 0; r < 4; r++) rs[r] += __shfl_xor(rs[r], off, 64);
    #pragma unroll
    for (int r = 0; r < 4; r++) l_run[r] = l_run[r] * al[r] + rs[r];
    #pragma unroll
    for (int dt = 0; dt < 4; dt++)
      #pragma unroll
      for (int r = 0; r < 4; r++) O[dt][r] *= al[r];

    // P: C-layout -> LDS -> A-operand layout (verified round-trip, m120)
    __bf16* pw = &Pw[wid][0];
    #pragma unroll
    for (int nt = 0; nt < 4; nt++)
      #pragma unroll
      for (int r = 0; r < 4; r++)
        pw[(quad * 4 + r) * LD + nt * 16 + l15] = f2bf(S[nt][r]);
    __syncthreads();

    // O += P.V  (A=P: m=row,k=s ; B from Vt: n=d, k=s, contiguous b128)
    #pragma unroll
    for (int ks = 0; ks < 2; ks++){
      bf16x8 ap = *(const bf16x8*)&pw[l15 * LD + ks * 32 + quad * 8];
      #pragma unroll
      for (int dt = 0; dt < 4; dt++){
        bf16x8 bv = *(const bf16x8*)&Vt[(dt * 16 + l15) * LD + ks * 32 + quad * 8];
        O[dt] = __builtin_amdgcn_mfma_f32_16x16x32_bf16(ap, bv, O[dt], 0, 0, 0);
      }
    }
  }

  // epilogue: ctx[(t*B+b), h*64+d] bf16 for the final GEMM
  #pragma unroll
  for (int dt = 0; dt < 4; dt++)
    #pragma unroll
    for (int r = 0; r < 4; r++){
      int t = t0 + quad * 4 + r;
      int d = dt * 16 + l15;
      float v = O[dt][r] / l_run[r];
      ctx[(size_t)(t * B_ + b) * E_ + h * DH_ + d] = f2bf(v);
    }
}

extern "C" void kernel_launch(void* const* d_in, const int* in_sizes, int n_in,
                              void* d_out, int out_size, void* d_ws, size_t ws_size,
                              hipStream_t stream)
{
  (void)in_sizes; (void)n_in; (void)out_size; (void)ws_size;
  const float* query    = (const float*)d_in[0];
  const float* q_w      = (const float*)d_in[1];
  const float* q_b      = (const float*)d_in[2];
  const float* k_w      = (const float*)d_in[3];
  const float* k_b      = (const float*)d_in[4];
  const float* v_w      = (const float*)d_in[5];
  const float* v_b      = (const float*)d_in[6];
  const float* out_w    = (const float*)d_in[7];
  const float* out_b    = (const float*)d_in[8];
  const float* rel_bias = (const float*)d_in[9];
  const float* grep_w   = (const float*)d_in[10];
  const float* grep_b   = (const float*)d_in[11];
  const float* grep_a   = (const float*)d_in[12];

  // workspace layout (~50.7 MB total)
  char* ws = (char*)d_ws;
  size_t off = 0;
  __bf16* qbf = (__bf16*)(ws + off); off += (size_t)4096 * 1024 * 2;   // query bf16 (TB, E)
  __bf16* wq  = (__bf16*)(ws + off); off += (size_t)1024 * 1024 * 2;
  __bf16* wk  = (__bf16*)(ws + off); off += (size_t)1024 * 1024 * 2;
  __bf16* wv  = (__bf16*)(ws + off); off += (size_t)1024 * 1024 * 2;
  __bf16* wo  = (__bf16*)(ws + off); off += (size_t)1024 * 1024 * 2;
  __bf16* qh  = (__bf16*)(ws + off); off += (size_t)4096 * 1024 * 2;   // (B,H,T,DH)
  __bf16* kh  = (__bf16*)(ws + off); off += (size_t)4096 * 1024 * 2;
  __bf16* vh  = (__bf16*)(ws + off); off += (size_t)4096 * 1024 * 2;
  __bf16* ctx = (__bf16*)(ws + off); off += (size_t)4096 * 1024 * 2;   // (TB, E)
  float* gates = (float*)(ws + off); off += (size_t)65536 * 4;         // (B*H, T)
  float* tab   = (float*)(ws + off); off += (size_t)16 * 2047 * 4;     // (H, 2047)

  cvt_bf16_kernel<<<4096, 256, 0, stream>>>(query, qbf, 4096 * 1024);
  cvt_bf16_kernel<<<1024, 256, 0, stream>>>(q_w,  wq, 1024 * 1024);
  cvt_bf16_kernel<<<1024, 256, 0, stream>>>(k_w,  wk, 1024 * 1024);
  cvt_bf16_kernel<<<1024, 256, 0, stream>>>(v_w,  wv, 1024 * 1024);
  cvt_bf16_kernel<<<1024, 256, 0, stream>>>(out_w, wo, 1024 * 1024);
  gates_kernel<<<256, 256, 0, stream>>>(query, grep_w, grep_b, grep_a, gates);
  tab_kernel<<<dim3(8, 16), 256, 0, stream>>>(rel_bias, tab);
  gemm_kernel<0><<<dim3(8, 32, 3), 256, 0, stream>>>(qbf, wq, wk, wv, q_b, k_b, v_b, qh, kh, vh);
  attn_kernel<<<dim3(16, 64), 256, 0, stream>>>(qh, kh, vh, gates, tab, ctx);
  gemm_kernel<1><<<dim3(8, 32, 1), 256, 0, stream>>>(ctx, wo, wo, wo, out_b, out_b, out_b,
                                                     d_out, d_out, d_out);
}

// Round 2
// 234.879 us; speedup vs baseline: 1.0924x; 1.0924x over previous
//
#include <hip/hip_runtime.h>
#include <math.h>

// Problem constants (reference: T,B,E,H = 1024,4,1024,16; DH=64; 32 buckets, max_dist 128)
#define T_ 1024
#define B_ 4
#define E_ 1024
#define H_ 16
#define DH_ 64

#define LOG2E 1.44269504088896f

typedef __attribute__((ext_vector_type(8))) __bf16 bf16x8;
typedef __attribute__((ext_vector_type(4))) __bf16 bf16x4;
typedef __attribute__((ext_vector_type(4))) float f32x4;

// fp32 -> bf16 round-to-nearest-even
__device__ __forceinline__ __bf16 f2bf(float x){
  union { unsigned short u; __bf16 b; } cv;
  unsigned u32 = __float_as_uint(x);
  cv.u = (unsigned short)((u32 + 0x7fffu + ((u32 >> 16) & 1u)) >> 16);
  return cv.b;
}
// fp32 -> bf16 round-half-up (2 VALU ops; used only for P in [0,1])
__device__ __forceinline__ __bf16 f2bf_fast(float x){
  union { unsigned short u; __bf16 b; } cv;
  cv.u = (unsigned short)((__float_as_uint(x) + 0x8000u) >> 16);
  return cv.b;
}

// async global->LDS, 16B per lane; LDS dest is wave-uniform base + lane*16 (m97/m104)
__device__ __forceinline__ void glds16(const void* g, void* l){
  __builtin_amdgcn_global_load_lds(
      (__attribute__((address_space(1))) void*)(void*)g,
      (__attribute__((address_space(3))) void*)l,
      16, 0, 0);
}

// ---------------- 4 weight matrices fp32->bf16 in one launch (grid.y selects) ----------------
__global__ void cvt4_kernel(const float* __restrict__ a0, const float* __restrict__ a1,
                            const float* __restrict__ a2, const float* __restrict__ a3,
                            __bf16* __restrict__ o0, __bf16* __restrict__ o1,
                            __bf16* __restrict__ o2, __bf16* __restrict__ o3){
  const float* a; __bf16* o;
  switch (blockIdx.y){
    case 0: a = a0; o = o0; break;
    case 1: a = a1; o = o1; break;
    case 2: a = a2; o = o2; break;
    default: a = a3; o = o3; break;
  }
  int i = (blockIdx.x * 256 + threadIdx.x) * 4;
  float4 v = *(const float4*)(a + i);
  bf16x4 r;
  r[0] = f2bf(v.x); r[1] = f2bf(v.y); r[2] = f2bf(v.z); r[3] = f2bf(v.w);
  *(bf16x4*)(o + i) = r;
}

// ---------------- gates + query bf16 conversion, fused ----------------
// wave = one query row t (64 lanes = 64 bh); coalesced 16KB row read, writes qbf + gates*log2e.
__global__ __launch_bounds__(256) void gates_kernel(
    const float* __restrict__ query, const float* __restrict__ gw,
    const float* __restrict__ gb, const float* __restrict__ ga,
    float* __restrict__ gates, __bf16* __restrict__ qbf){
  int t = blockIdx.x * 4 + (threadIdx.x >> 6);
  int bh = threadIdx.x & 63;
  int h = bh & 15;
  const float* q = query + (size_t)t * E_ * B_ + bh * 64;   // query[t][b][h*64+d] = [t*4096 + bh*64 + d]
  __bf16* qo = qbf + (size_t)t * E_ * B_ + bh * 64;
  float g[8];
  #pragma unroll
  for (int e = 0; e < 8; e++) g[e] = gb[e];
  #pragma unroll
  for (int c = 0; c < 8; c++){
    float4 v0 = *(const float4*)(q + c * 8);
    float4 v1 = *(const float4*)(q + c * 8 + 4);
    bf16x8 o;
    o[0] = f2bf(v0.x); o[1] = f2bf(v0.y); o[2] = f2bf(v0.z); o[3] = f2bf(v0.w);
    o[4] = f2bf(v1.x); o[5] = f2bf(v1.y); o[6] = f2bf(v1.z); o[7] = f2bf(v1.w);
    *(bf16x8*)(qo + c * 8) = o;
    #pragma unroll
    for (int e = 0; e < 8; e++){
      const float* w = gw + e * 64 + c * 8;     // uniform -> s_load
      g[e] += v0.x * w[0] + v0.y * w[1] + v0.z * w[2] + v0.w * w[3]
            + v1.x * w[4] + v1.y * w[5] + v1.z * w[6] + v1.w * w[7];
    }
  }
  float a0 = (g[0] + g[1]) + (g[2] + g[3]);
  float a1 = (g[4] + g[5]) + (g[6] + g[7]);
  float sa = 1.f / (1.f + __expf(-a0));
  float sb = 1.f / (1.f + __expf(-a1));
  gates[bh * T_ + t] = (sa * (sb * ga[h] - 1.0f) + 2.0f) * LOG2E;   // pre-scaled for exp2 softmax
}

// ---------------- relative-position bias table (bf16): tab[h][rp+1023] ----------------
__global__ void tab_kernel(const float* __restrict__ rel_bias, __bf16* __restrict__ tab){
  int i = blockIdx.x * 256 + threadIdx.x;
  if (i >= 2047) return;
  int h = blockIdx.y;
  int rp = i - 1023;                 // rp = s - t
  int base = rp > 0 ? 16 : 0;
  int arp = rp < 0 ? -rp : rp;
  int off;
  if (arp < 8) off = arp;
  else {
    float val = (logf((float)arp * 0.125f) / 2.772588722239781f) * 8.0f;
    int lg = (int)val;
    off = 8 + (lg > 7 ? 7 : lg);
  }
  tab[h * 2047 + i] = f2bf(rel_bias[(base + off) * H_ + h]);
}

// ---------------- bf16 MFMA GEMM: C[m,n] = (sum_k A[m,k]*W[n,k] + bias[n]) * scale ----------------
// MODE 0: z in {0,1,2} -> q (scale=0.125*log2e) / k / v; q,k scatter to (B,H,T,DH); v to (B,H,DH,T).
// MODE 1: plain fp32 row-major write (final out-proj).
template<int MODE>
__global__ __launch_bounds__(256) void gemm_kernel(
    const __bf16* __restrict__ A,
    const __bf16* __restrict__ W0, const __bf16* __restrict__ W1, const __bf16* __restrict__ W2,
    const float* __restrict__ b0, const float* __restrict__ b1, const float* __restrict__ b2,
    void* out0, void* out1, void* out2)
{
  __shared__ __bf16 As[128 * 32];   // unpadded: required by global_load_lds
  __shared__ __bf16 Bs[128 * 32];
  const int tid = threadIdx.x;
  const int lane = tid & 63, wid = tid >> 6;
  const int l15 = lane & 15, quad = lane >> 4;
  const int wm = wid >> 1, wn = wid & 1;
  const int m0 = blockIdx.y * 128, n0 = blockIdx.x * 128;

  const __bf16* W = W0;
  const float* bias = b0;
  float scale = 1.0f;
  void* outp = out0;
  if (MODE == 0){
    int z = blockIdx.z;
    if (z == 0){ scale = 0.125f * LOG2E; }               // q: *DH^-0.5 * log2e (exp2 softmax)
    else if (z == 1){ W = W1; bias = b1; outp = out1; }  // k
    else            { W = W2; bias = b2; outp = out2; }  // v (transposed write)
  }

  f32x4 acc[4][4];
  #pragma unroll
  for (int i = 0; i < 4; i++)
    #pragma unroll
    for (int j = 0; j < 4; j++){
      acc[i][j][0] = 0.f; acc[i][j][1] = 0.f; acc[i][j][2] = 0.f; acc[i][j][3] = 0.f;
    }

  const int grow = lane >> 2;
  const int gcol = (lane & 3) * 8;

  for (int k0 = 0; k0 < E_; k0 += 32){
    __syncthreads();
    #pragma unroll
    for (int r2 = 0; r2 < 2; r2++){
      int rb = (wid * 2 + r2) * 16;
      glds16(A + (size_t)(m0 + rb + grow) * E_ + k0 + gcol, &As[rb * 32]);
      glds16(W + (size_t)(n0 + rb + grow) * E_ + k0 + gcol, &Bs[rb * 32]);
    }
    __syncthreads();
    bf16x8 am[4], bn[4];
    #pragma unroll
    for (int i = 0; i < 4; i++) am[i] = *(const bf16x8*)&As[(wm * 64 + i * 16 + l15) * 32 + quad * 8];
    #pragma unroll
    for (int j = 0; j < 4; j++) bn[j] = *(const bf16x8*)&Bs[(wn * 64 + j * 16 + l15) * 32 + quad * 8];
    #pragma unroll
    for (int i = 0; i < 4; i++)
      #pragma unroll
      for (int j = 0; j < 4; j++)
        acc[i][j] = __builtin_amdgcn_mfma_f32_16x16x32_bf16(am[i], bn[j], acc[i][j], 0, 0, 0);
  }

  // epilogue: C/D layout col=lane&15, row=quad*4+reg (m89/m91)
  #pragma unroll
  for (int i = 0; i < 4; i++){
    const int row0 = m0 + wm * 64 + i * 16 + quad * 4;   // multiple of 4 -> t fixed, r = batch
    #pragma unroll
    for (int j = 0; j < 4; j++){
      const int col = n0 + wn * 64 + j * 16 + l15;
      const float bc = bias[col];
      #pragma unroll
      for (int r = 0; r < 4; r++){
        float v = (acc[i][j][r] + bc) * scale;
        int row = row0 + r;
        if (MODE == 0){
          int t = row >> 2, bb = row & 3;       // m = t*B + b
          int hh = col >> 6, d = col & 63;      // n = h*DH + d
          if (blockIdx.z == 2)                  // v: (B,H,DH,T) for transpose-free attn staging
            ((__bf16*)outp)[(size_t)((bb * H_ + hh) * DH_ + d) * T_ + t] = f2bf(v);
          else
            ((__bf16*)outp)[(size_t)((bb * H_ + hh) * T_ + t) * DH_ + d] = f2bf(v);
        } else {
          ((float*)outp)[(size_t)row * E_ + col] = v;
        }
      }
    }
  }
}

// ---------------- flash attention v2: S^T orientation, bf16 MFMA, exp2 online softmax ----------------
// grid (T/64, B*H); block 256 = 4 waves; wave owns 16 t-cols (n dim); s-tiles of 64 (m dim).
// Lane t = t0 + (lane&15): softmax state is one scalar per lane; reductions are 2 cross-quad shuffles.
__global__ __launch_bounds__(256) void attn_kernel(
    const __bf16* __restrict__ qg, const __bf16* __restrict__ kg, const __bf16* __restrict__ vgT,
    const float* __restrict__ gates, const __bf16* __restrict__ tab,
    __bf16* __restrict__ ctx)
{
  const int LD = 72;                  // 144B rows: frag reads ~2-way conflicts
  __shared__ __bf16 Ks[64 * LD];      // K-tile (s, d)
  __shared__ __bf16 Vt[64 * LD];      // V^T tile (d, s) — staged directly (global is (B,H,DH,T))
  __shared__ __bf16 Pt[4][16 * LD];   // per-wave P^T, t-major: [t][s] — NO barrier needed
  __shared__ __bf16 tabh[2048];       // rel-bias row for this h (bf16)

  const int tid = threadIdx.x;
  const int lane = tid & 63, wid = tid >> 6;
  const int l15 = lane & 15, quad = lane >> 4;
  const int bh = blockIdx.y;
  const int b = bh >> 4, h = bh & 15;
  const __bf16* qb = qg + (size_t)bh * T_ * DH_;
  const __bf16* kb = kg + (size_t)bh * T_ * DH_;
  const __bf16* vb = vgT + (size_t)bh * DH_ * T_;

  for (int i = tid; i < 2047; i += 256) tabh[i] = tab[h * 2047 + i];

  const int t0 = blockIdx.x * 64 + wid * 16;
  const int t_lane = t0 + l15;
  // Q as B-operand: B[k=quad*8+j][n=l15] = Q[t_lane][quad*8+j] — direct from global, loop-invariant
  bf16x8 bq0 = *(const bf16x8*)(qb + (size_t)t_lane * DH_ + quad * 8);
  bf16x8 bq1 = *(const bf16x8*)(qb + (size_t)t_lane * DH_ + 32 + quad * 8);
  const float g = gates[bh * T_ + t_lane];      // already * log2e
  const int ibase0 = 1023 - t_lane;

  float m_run = -INFINITY, l_run = 0.f;
  f32x4 O[4];
  #pragma unroll
  for (int mt = 0; mt < 4; mt++){ O[mt][0] = 0.f; O[mt][1] = 0.f; O[mt][2] = 0.f; O[mt][3] = 0.f; }

  for (int s0 = 0; s0 < T_; s0 += 64){
    __syncthreads();                  // prev-iter LDS reads done before restage
    #pragma unroll
    for (int r2 = 0; r2 < 2; r2++){
      int cid = r2 * 256 + tid;       // 512 x 16B chunks each for K and V^T
      int row = cid >> 3, c = cid & 7;
      *(bf16x8*)&Ks[row * LD + c * 8] = *(const bf16x8*)(kb + (size_t)(s0 + row) * DH_ + c * 8);
      *(bf16x8*)&Vt[row * LD + c * 8] = *(const bf16x8*)(vb + (size_t)row * T_ + s0 + c * 8);
    }
    __syncthreads();

    // S^T = K.Q^T : A=K (m=s), B=Q^T (n=t). D: S^T[s=nt*16+quad*4+r][t=l15]
    f32x4 S[4];
    #pragma unroll
    for (int nt = 0; nt < 4; nt++){
      bf16x8 ak0 = *(const bf16x8*)&Ks[(nt * 16 + l15) * LD + quad * 8];
      bf16x8 ak1 = *(const bf16x8*)&Ks[(nt * 16 + l15) * LD + 32 + quad * 8];
      f32x4 a; a[0] = 0.f; a[1] = 0.f; a[2] = 0.f; a[3] = 0.f;
      a = __builtin_amdgcn_mfma_f32_16x16x32_bf16(ak0, bq0, a, 0, 0, 0);
      a = __builtin_amdgcn_mfma_f32_16x16x32_bf16(ak1, bq1, a, 0, 0, 0);
      S[nt] = a;
    }
    // bias: S^T[s][t] += g * tab[s - t + 1023]   (g pre-scaled by log2e; S already log2e-scaled)
    const int ib = ibase0 + s0;
    #pragma unroll
    for (int nt = 0; nt < 4; nt++)
      #pragma unroll
      for (int r = 0; r < 4; r++)
        S[nt][r] += g * (float)tabh[ib + nt * 16 + quad * 4 + r];

    // online softmax over s (per-lane scalar state; cross-quad reduce = 2 shuffles)
    float mx = S[0][0];
    #pragma unroll
    for (int nt = 0; nt < 4; nt++)
      #pragma unroll
      for (int r = 0; r < 4; r++) mx = fmaxf(mx, S[nt][r]);
    mx = fmaxf(mx, __shfl_xor(mx, 16, 64));
    mx = fmaxf(mx, __shfl_xor(mx, 32, 64));
    float mnew = fmaxf(m_run, mx);
    float al = __builtin_amdgcn_exp2f(m_run - mnew);
    m_run = mnew;
    #pragma unroll
    for (int nt = 0; nt < 4; nt++)
      #pragma unroll
      for (int r = 0; r < 4; r++) S[nt][r] = __builtin_amdgcn_exp2f(S[nt][r] - m_run);
    float rs = 0.f;
    #pragma unroll
    for (int nt = 0; nt < 4; nt++) rs += (S[nt][0] + S[nt][1]) + (S[nt][2] + S[nt][3]);
    rs += __shfl_xor(rs, 16, 64);
    rs += __shfl_xor(rs, 32, 64);
    l_run = l_run * al + rs;
    #pragma unroll
    for (int mt = 0; mt < 4; mt++){
      O[mt][0] *= al; O[mt][1] *= al; O[mt][2] *= al; O[mt][3] *= al;
    }

    // P^T -> per-wave LDS (t-major): b64 writes; wave-local, compiler orders via lgkmcnt
    __bf16* pw = &Pt[wid][0];
    #pragma unroll
    for (int nt = 0; nt < 4; nt++){
      bf16x4 p;
      p[0] = f2bf_fast(S[nt][0]); p[1] = f2bf_fast(S[nt][1]);
      p[2] = f2bf_fast(S[nt][2]); p[3] = f2bf_fast(S[nt][3]);
      *(bf16x4*)&pw[l15 * LD + nt * 16 + quad * 4] = p;
    }

    // O^T += V^T . P^T : A=V^T (m=d), B=P^T (n=t). D: O^T[d=mt*16+quad*4+r][t=l15]
    #pragma unroll
    for (int ks = 0; ks < 2; ks++){
      bf16x8 bp = *(const bf16x8*)&pw[l15 * LD + ks * 32 + quad * 8];
      #pragma unroll
      for (int mt = 0; mt < 4; mt++){
        bf16x8 av = *(const bf16x8*)&Vt[(mt * 16 + l15) * LD + ks * 32 + quad * 8];
        O[mt] = __builtin_amdgcn_mfma_f32_16x16x32_bf16(av, bp, O[mt], 0, 0, 0);
      }
    }
  }

  // epilogue: ctx[(t*B+b)*E + h*64+d], d = mt*16+quad*4+r -> bf16x4 stores
  const float inv = 1.f / l_run;
  #pragma unroll
  for (int mt = 0; mt < 4; mt++){
    bf16x4 o;
    o[0] = f2bf(O[mt][0] * inv); o[1] = f2bf(O[mt][1] * inv);
    o[2] = f2bf(O[mt][2] * inv); o[3] = f2bf(O[mt][3] * inv);
    *(bf16x4*)&ctx[(size_t)(t_lane * B_ + b) * E_ + h * DH_ + mt * 16 + quad * 4] = o;
  }
}

extern "C" void kernel_launch(void* const* d_in, const int* in_sizes, int n_in,
                              void* d_out, int out_size, void* d_ws, size_t ws_size,
                              hipStream_t stream)
{
  (void)in_sizes; (void)n_in; (void)out_size; (void)ws_size;
  const float* query    = (const float*)d_in[0];
  const float* q_w      = (const float*)d_in[1];
  const float* q_b      = (const float*)d_in[2];
  const float* k_w      = (const float*)d_in[3];
  const float* k_b      = (const float*)d_in[4];
  const float* v_w      = (const float*)d_in[5];
  const float* v_b      = (const float*)d_in[6];
  const float* out_w    = (const float*)d_in[7];
  const float* out_b    = (const float*)d_in[8];
  const float* rel_bias = (const float*)d_in[9];
  const float* grep_w   = (const float*)d_in[10];
  const float* grep_b   = (const float*)d_in[11];
  const float* grep_a   = (const float*)d_in[12];

  char* ws = (char*)d_ws;
  size_t off = 0;
  __bf16* qbf = (__bf16*)(ws + off); off += (size_t)4096 * 1024 * 2;   // query bf16 (TB, E)
  __bf16* wq  = (__bf16*)(ws + off); off += (size_t)1024 * 1024 * 2;
  __bf16* wk  = (__bf16*)(ws + off); off += (size_t)1024 * 1024 * 2;
  __bf16* wv  = (__bf16*)(ws + off); off += (size_t)1024 * 1024 * 2;
  __bf16* wo  = (__bf16*)(ws + off); off += (size_t)1024 * 1024 * 2;
  __bf16* qh  = (__bf16*)(ws + off); off += (size_t)4096 * 1024 * 2;   // (B,H,T,DH)
  __bf16* kh  = (__bf16*)(ws + off); off += (size_t)4096 * 1024 * 2;   // (B,H,T,DH)
  __bf16* vhT = (__bf16*)(ws + off); off += (size_t)4096 * 1024 * 2;   // (B,H,DH,T)
  __bf16* ctx = (__bf16*)(ws + off); off += (size_t)4096 * 1024 * 2;   // (TB, E)
  float* gates = (float*)(ws + off); off += (size_t)65536 * 4;         // (B*H, T), * log2e
  __bf16* tab  = (__bf16*)(ws + off); off += (size_t)16 * 2047 * 2;    // (H, 2047) bf16

  cvt4_kernel<<<dim3(1024, 4), 256, 0, stream>>>(q_w, k_w, v_w, out_w, wq, wk, wv, wo);
  gates_kernel<<<256, 256, 0, stream>>>(query, grep_w, grep_b, grep_a, gates, qbf);
  tab_kernel<<<dim3(8, 16), 256, 0, stream>>>(rel_bias, tab);
  gemm_kernel<0><<<dim3(8, 32, 3), 256, 0, stream>>>(qbf, wq, wk, wv, q_b, k_b, v_b, qh, kh, vhT);
  attn_kernel<<<dim3(16, 64), 256, 0, stream>>>(qh, kh, vhT, gates, tab, ctx);
  gemm_kernel<1><<<dim3(8, 32, 1), 256, 0, stream>>>(ctx, wo, wo, wo, out_b, out_b, out_b,
                                                     d_out, d_out, d_out);
}

// Round 3
// 229.124 us; speedup vs baseline: 1.1198x; 1.0251x over previous
//
#include <hip/hip_runtime.h>
#include <math.h>

// Problem constants (reference: T,B,E,H = 1024,4,1024,16; DH=64; 32 buckets, max_dist 128)
#define T_ 1024
#define B_ 4
#define E_ 1024
#define H_ 16
#define DH_ 64

#define LOG2E 1.44269504088896f

typedef __attribute__((ext_vector_type(8))) __bf16 bf16x8;
typedef __attribute__((ext_vector_type(4))) __bf16 bf16x4;
typedef __attribute__((ext_vector_type(4))) float f32x4;

// fp32 -> bf16 round-to-nearest-even
__device__ __forceinline__ __bf16 f2bf(float x){
  union { unsigned short u; __bf16 b; } cv;
  unsigned u32 = __float_as_uint(x);
  cv.u = (unsigned short)((u32 + 0x7fffu + ((u32 >> 16) & 1u)) >> 16);
  return cv.b;
}
// fp32 -> bf16 round-half-up (cheaper; used only for P >= 0)
__device__ __forceinline__ __bf16 f2bf_fast(float x){
  union { unsigned short u; __bf16 b; } cv;
  cv.u = (unsigned short)((__float_as_uint(x) + 0x8000u) >> 16);
  return cv.b;
}

// async global->LDS, 16B per lane; LDS dest is wave-uniform base + lane*16 (m97/m104)
__device__ __forceinline__ void glds16(const void* g, void* l){
  __builtin_amdgcn_global_load_lds(
      (__attribute__((address_space(1))) void*)(void*)g,
      (__attribute__((address_space(3))) void*)l,
      16, 0, 0);
}

// ---------------- 4 weight matrices fp32->bf16 in one launch (grid.y selects) ----------------
__global__ void cvt4_kernel(const float* __restrict__ a0, const float* __restrict__ a1,
                            const float* __restrict__ a2, const float* __restrict__ a3,
                            __bf16* __restrict__ o0, __bf16* __restrict__ o1,
                            __bf16* __restrict__ o2, __bf16* __restrict__ o3){
  const float* a; __bf16* o;
  switch (blockIdx.y){
    case 0: a = a0; o = o0; break;
    case 1: a = a1; o = o1; break;
    case 2: a = a2; o = o2; break;
    default: a = a3; o = o3; break;
  }
  int i = (blockIdx.x * 256 + threadIdx.x) * 4;
  float4 v = *(const float4*)(a + i);
  bf16x4 r;
  r[0] = f2bf(v.x); r[1] = f2bf(v.y); r[2] = f2bf(v.z); r[3] = f2bf(v.w);
  *(bf16x4*)(o + i) = r;
}

// ---------------- gates + query bf16 conversion, fused ----------------
__global__ __launch_bounds__(256) void gates_kernel(
    const float* __restrict__ query, const float* __restrict__ gw,
    const float* __restrict__ gb, const float* __restrict__ ga,
    float* __restrict__ gates, __bf16* __restrict__ qbf){
  int t = blockIdx.x * 4 + (threadIdx.x >> 6);
  int bh = threadIdx.x & 63;
  int h = bh & 15;
  const float* q = query + (size_t)t * E_ * B_ + bh * 64;
  __bf16* qo = qbf + (size_t)t * E_ * B_ + bh * 64;
  float g[8];
  #pragma unroll
  for (int e = 0; e < 8; e++) g[e] = gb[e];
  #pragma unroll
  for (int c = 0; c < 8; c++){
    float4 v0 = *(const float4*)(q + c * 8);
    float4 v1 = *(const float4*)(q + c * 8 + 4);
    bf16x8 o;
    o[0] = f2bf(v0.x); o[1] = f2bf(v0.y); o[2] = f2bf(v0.z); o[3] = f2bf(v0.w);
    o[4] = f2bf(v1.x); o[5] = f2bf(v1.y); o[6] = f2bf(v1.z); o[7] = f2bf(v1.w);
    *(bf16x8*)(qo + c * 8) = o;
    #pragma unroll
    for (int e = 0; e < 8; e++){
      const float* w = gw + e * 64 + c * 8;     // uniform -> s_load
      g[e] += v0.x * w[0] + v0.y * w[1] + v0.z * w[2] + v0.w * w[3]
            + v1.x * w[4] + v1.y * w[5] + v1.z * w[6] + v1.w * w[7];
    }
  }
  float a0 = (g[0] + g[1]) + (g[2] + g[3]);
  float a1 = (g[4] + g[5]) + (g[6] + g[7]);
  float sa = 1.f / (1.f + __expf(-a0));
  float sb = 1.f / (1.f + __expf(-a1));
  gates[bh * T_ + t] = (sa * (sb * ga[h] - 1.0f) + 2.0f) * LOG2E;   // pre-scaled for exp2 softmax
}

// ---------------- relative-position bias table (bf16): tab[h][rp+1023] ----------------
__global__ void tab_kernel(const float* __restrict__ rel_bias, __bf16* __restrict__ tab){
  int i = blockIdx.x * 256 + threadIdx.x;
  if (i >= 2047) return;
  int h = blockIdx.y;
  int rp = i - 1023;
  int base = rp > 0 ? 16 : 0;
  int arp = rp < 0 ? -rp : rp;
  int off;
  if (arp < 8) off = arp;
  else {
    float val = (logf((float)arp * 0.125f) / 2.772588722239781f) * 8.0f;
    int lg = (int)val;
    off = 8 + (lg > 7 ? 7 : lg);
  }
  tab[h * 2047 + i] = f2bf(rel_bias[(base + off) * H_ + h]);
}

// ---------------- QKV GEMM: 128x128 tile, z selects q/k/v; scatter-write bf16 ----------------
__global__ __launch_bounds__(256) void gemm_qkv(
    const __bf16* __restrict__ A,
    const __bf16* __restrict__ W0, const __bf16* __restrict__ W1, const __bf16* __restrict__ W2,
    const float* __restrict__ b0, const float* __restrict__ b1, const float* __restrict__ b2,
    __bf16* out0, __bf16* out1, __bf16* out2)
{
  __shared__ __bf16 As[128 * 32];   // unpadded: required by global_load_lds
  __shared__ __bf16 Bs[128 * 32];
  const int tid = threadIdx.x;
  const int lane = tid & 63, wid = tid >> 6;
  const int l15 = lane & 15, quad = lane >> 4;
  const int wm = wid >> 1, wn = wid & 1;
  const int m0 = blockIdx.y * 128, n0 = blockIdx.x * 128;

  const __bf16* W = W0;
  const float* bias = b0;
  float scale = 1.0f;
  __bf16* outp = out0;
  int z = blockIdx.z;
  if (z == 0){ scale = 0.125f * LOG2E; }               // q: *DH^-0.5 * log2e
  else if (z == 1){ W = W1; bias = b1; outp = out1; }  // k
  else            { W = W2; bias = b2; outp = out2; }  // v (transposed write)

  f32x4 acc[4][4];
  #pragma unroll
  for (int i = 0; i < 4; i++)
    #pragma unroll
    for (int j = 0; j < 4; j++){
      acc[i][j][0] = 0.f; acc[i][j][1] = 0.f; acc[i][j][2] = 0.f; acc[i][j][3] = 0.f;
    }

  const int grow = lane >> 2;
  const int gcol = (lane & 3) * 8;

  for (int k0 = 0; k0 < E_; k0 += 32){
    __syncthreads();
    #pragma unroll
    for (int r2 = 0; r2 < 2; r2++){
      int rb = (wid * 2 + r2) * 16;
      glds16(A + (size_t)(m0 + rb + grow) * E_ + k0 + gcol, &As[rb * 32]);
      glds16(W + (size_t)(n0 + rb + grow) * E_ + k0 + gcol, &Bs[rb * 32]);
    }
    __syncthreads();
    bf16x8 am[4], bn[4];
    #pragma unroll
    for (int i = 0; i < 4; i++) am[i] = *(const bf16x8*)&As[(wm * 64 + i * 16 + l15) * 32 + quad * 8];
    #pragma unroll
    for (int j = 0; j < 4; j++) bn[j] = *(const bf16x8*)&Bs[(wn * 64 + j * 16 + l15) * 32 + quad * 8];
    #pragma unroll
    for (int i = 0; i < 4; i++)
      #pragma unroll
      for (int j = 0; j < 4; j++)
        acc[i][j] = __builtin_amdgcn_mfma_f32_16x16x32_bf16(am[i], bn[j], acc[i][j], 0, 0, 0);
  }

  #pragma unroll
  for (int i = 0; i < 4; i++){
    const int row0 = m0 + wm * 64 + i * 16 + quad * 4;
    #pragma unroll
    for (int j = 0; j < 4; j++){
      const int col = n0 + wn * 64 + j * 16 + l15;
      const float bc = bias[col];
      #pragma unroll
      for (int r = 0; r < 4; r++){
        float v = (acc[i][j][r] + bc) * scale;
        int row = row0 + r;
        int t = row >> 2, bb = row & 3;       // m = t*B + b
        int hh = col >> 6, d = col & 63;      // n = h*DH + d
        if (z == 2)                           // v: (B,H,DH,T)
          outp[(size_t)((bb * H_ + hh) * DH_ + d) * T_ + t] = f2bf(v);
        else
          outp[(size_t)((bb * H_ + hh) * T_ + t) * DH_ + d] = f2bf(v);
      }
    }
  }
}

// ---------------- out-proj GEMM: 64x128 tile (2 blocks/CU for occupancy), fp32 write ----------------
__global__ __launch_bounds__(256) void gemm_out(
    const __bf16* __restrict__ A, const __bf16* __restrict__ W,
    const float* __restrict__ bias, float* __restrict__ out)
{
  __shared__ __bf16 As[64 * 32];
  __shared__ __bf16 Bs[128 * 32];
  const int tid = threadIdx.x;
  const int lane = tid & 63, wid = tid >> 6;
  const int l15 = lane & 15, quad = lane >> 4;
  const int wm = wid >> 1, wn = wid & 1;
  const int m0 = blockIdx.y * 64, n0 = blockIdx.x * 128;

  f32x4 acc[2][4];
  #pragma unroll
  for (int i = 0; i < 2; i++)
    #pragma unroll
    for (int j = 0; j < 4; j++){
      acc[i][j][0] = 0.f; acc[i][j][1] = 0.f; acc[i][j][2] = 0.f; acc[i][j][3] = 0.f;
    }

  const int grow = lane >> 2;
  const int gcol = (lane & 3) * 8;

  for (int k0 = 0; k0 < E_; k0 += 32){
    __syncthreads();
    glds16(A + (size_t)(m0 + wid * 16 + grow) * E_ + k0 + gcol, &As[wid * 16 * 32]);
    #pragma unroll
    for (int r2 = 0; r2 < 2; r2++){
      int rb = (wid * 2 + r2) * 16;
      glds16(W + (size_t)(n0 + rb + grow) * E_ + k0 + gcol, &Bs[rb * 32]);
    }
    __syncthreads();
    bf16x8 am[2], bn[4];
    #pragma unroll
    for (int i = 0; i < 2; i++) am[i] = *(const bf16x8*)&As[(wm * 32 + i * 16 + l15) * 32 + quad * 8];
    #pragma unroll
    for (int j = 0; j < 4; j++) bn[j] = *(const bf16x8*)&Bs[(wn * 64 + j * 16 + l15) * 32 + quad * 8];
    #pragma unroll
    for (int i = 0; i < 2; i++)
      #pragma unroll
      for (int j = 0; j < 4; j++)
        acc[i][j] = __builtin_amdgcn_mfma_f32_16x16x32_bf16(am[i], bn[j], acc[i][j], 0, 0, 0);
  }

  #pragma unroll
  for (int i = 0; i < 2; i++){
    const int row0 = m0 + wm * 32 + i * 16 + quad * 4;
    #pragma unroll
    for (int j = 0; j < 4; j++){
      const int col = n0 + wn * 64 + j * 16 + l15;
      const float bc = bias[col];
      #pragma unroll
      for (int r = 0; r < 4; r++)
        out[(size_t)(row0 + r) * E_ + col] = acc[i][j][r] + bc;
    }
  }
}

// ---------------- flash attention v3: S^T orientation, no-max exp2 softmax, reg prefetch ----------------
// 1-D grid 1024 blocks; XCD swizzle pins all 16 t-blocks of one bh to one XCD (K/V L2-resident).
__global__ __launch_bounds__(256) void attn_kernel(
    const __bf16* __restrict__ qg, const __bf16* __restrict__ kg, const __bf16* __restrict__ vgT,
    const float* __restrict__ gates, const __bf16* __restrict__ tab,
    __bf16* __restrict__ ctx)
{
  const int LD = 72;                  // 144B rows
  __shared__ __bf16 Ks[64 * LD];      // K-tile (s, d)
  __shared__ __bf16 Vt[64 * LD];      // V^T tile (d, s)
  __shared__ __bf16 Pt[4][16 * LD];   // per-wave P^T (t-major) — wave-local, no barrier
  __shared__ __bf16 tabh[2048];

  const int tid = threadIdx.x;
  const int lane = tid & 63, wid = tid >> 6;
  const int l15 = lane & 15, quad = lane >> 4;
  // XCD-aware swizzle: d&7 = XCD slot; all t-blocks of a bh share it
  const int d = blockIdx.x;
  const int j = d >> 3;
  const int bh = (d & 7) + 8 * (j & 7);
  const int tq = j >> 3;              // 0..15
  const int b = bh >> 4, h = bh & 15;
  const __bf16* qb = qg + (size_t)bh * T_ * DH_;
  const __bf16* kb = kg + (size_t)bh * T_ * DH_;
  const __bf16* vb = vgT + (size_t)bh * DH_ * T_;

  for (int i = tid; i < 2047; i += 256) tabh[i] = tab[h * 2047 + i];

  const int t0 = tq * 64 + wid * 16;
  const int t_lane = t0 + l15;
  // Q as B-operand: loop-invariant, direct from global
  bf16x8 bq0 = *(const bf16x8*)(qb + (size_t)t_lane * DH_ + quad * 8);
  bf16x8 bq1 = *(const bf16x8*)(qb + (size_t)t_lane * DH_ + 32 + quad * 8);
  const float g = gates[bh * T_ + t_lane];      // already * log2e
  const int ibase0 = 1023 - t_lane;

  // staging assignment: thread covers chunks cid = tid and tid+256 (rows r0, r0+32)
  const int r0 = tid >> 3;
  const int c0 = (tid & 7) * 8;

  float l_run = 0.f;
  f32x4 O[4];
  #pragma unroll
  for (int mt = 0; mt < 4; mt++){ O[mt][0] = 0.f; O[mt][1] = 0.f; O[mt][2] = 0.f; O[mt][3] = 0.f; }

  // prefetch tile 0 into registers
  bf16x8 kA = *(const bf16x8*)(kb + (size_t)r0 * DH_ + c0);
  bf16x8 kB = *(const bf16x8*)(kb + (size_t)(r0 + 32) * DH_ + c0);
  bf16x8 vA = *(const bf16x8*)(vb + (size_t)r0 * T_ + c0);
  bf16x8 vB = *(const bf16x8*)(vb + (size_t)(r0 + 32) * T_ + c0);

  for (int s0 = 0; s0 < T_; s0 += 64){
    __syncthreads();                  // prev-iter LDS reads done before restage
    *(bf16x8*)&Ks[r0 * LD + c0] = kA;
    *(bf16x8*)&Ks[(r0 + 32) * LD + c0] = kB;
    *(bf16x8*)&Vt[r0 * LD + c0] = vA;
    *(bf16x8*)&Vt[(r0 + 32) * LD + c0] = vB;
    __syncthreads();

    // prefetch next tile (wraps to 0 at tail; discarded) — overlaps with compute below
    int sn = (s0 + 64) & (T_ - 1);
    kA = *(const bf16x8*)(kb + (size_t)(sn + r0) * DH_ + c0);
    kB = *(const bf16x8*)(kb + (size_t)(sn + r0 + 32) * DH_ + c0);
    vA = *(const bf16x8*)(vb + (size_t)r0 * T_ + sn + c0);
    vB = *(const bf16x8*)(vb + (size_t)(r0 + 32) * T_ + sn + c0);

    // S^T = K.Q^T : A=K (m=s), B=Q^T (n=t). D: S^T[s=nt*16+quad*4+r][t=l15]
    f32x4 S[4];
    #pragma unroll
    for (int nt = 0; nt < 4; nt++){
      bf16x8 ak0 = *(const bf16x8*)&Ks[(nt * 16 + l15) * LD + quad * 8];
      bf16x8 ak1 = *(const bf16x8*)&Ks[(nt * 16 + l15) * LD + 32 + quad * 8];
      f32x4 a; a[0] = 0.f; a[1] = 0.f; a[2] = 0.f; a[3] = 0.f;
      a = __builtin_amdgcn_mfma_f32_16x16x32_bf16(ak0, bq0, a, 0, 0, 0);
      a = __builtin_amdgcn_mfma_f32_16x16x32_bf16(ak1, bq1, a, 0, 0, 0);
      S[nt] = a;
    }
    // bias + exp2 (no max-shift: scores are O(10), fp32 exp2 safe; softmax shift-invariant)
    const int ib = ibase0 + s0;
    #pragma unroll
    for (int nt = 0; nt < 4; nt++)
      #pragma unroll
      for (int r = 0; r < 4; r++)
        S[nt][r] = __builtin_amdgcn_exp2f(S[nt][r] + g * (float)tabh[ib + nt * 16 + quad * 4 + r]);

    // P^T -> per-wave LDS (t-major): b64 writes, wave-local round-trip
    __bf16* pw = &Pt[wid][0];
    #pragma unroll
    for (int nt = 0; nt < 4; nt++){
      bf16x4 p;
      p[0] = f2bf_fast(S[nt][0]); p[1] = f2bf_fast(S[nt][1]);
      p[2] = f2bf_fast(S[nt][2]); p[3] = f2bf_fast(S[nt][3]);
      *(bf16x4*)&pw[l15 * LD + nt * 16 + quad * 4] = p;
    }

    // softmax denominator (off critical path; epilogue-only consumer)
    float rs = 0.f;
    #pragma unroll
    for (int nt = 0; nt < 4; nt++) rs += (S[nt][0] + S[nt][1]) + (S[nt][2] + S[nt][3]);
    rs += __shfl_xor(rs, 16, 64);
    rs += __shfl_xor(rs, 32, 64);
    l_run += rs;

    // O^T += V^T . P^T : A=V^T (m=d), B=P^T (n=t)
    #pragma unroll
    for (int ks = 0; ks < 2; ks++){
      bf16x8 bp = *(const bf16x8*)&pw[l15 * LD + ks * 32 + quad * 8];
      #pragma unroll
      for (int mt = 0; mt < 4; mt++){
        bf16x8 av = *(const bf16x8*)&Vt[(mt * 16 + l15) * LD + ks * 32 + quad * 8];
        O[mt] = __builtin_amdgcn_mfma_f32_16x16x32_bf16(av, bp, O[mt], 0, 0, 0);
      }
    }
  }

  // epilogue: ctx[(t*B+b)*E + h*64+d], d = mt*16+quad*4+r
  const float inv = 1.f / l_run;
  #pragma unroll
  for (int mt = 0; mt < 4; mt++){
    bf16x4 o;
    o[0] = f2bf(O[mt][0] * inv); o[1] = f2bf(O[mt][1] * inv);
    o[2] = f2bf(O[mt][2] * inv); o[3] = f2bf(O[mt][3] * inv);
    *(bf16x4*)&ctx[(size_t)(t_lane * B_ + b) * E_ + h * DH_ + mt * 16 + quad * 4] = o;
  }
}

extern "C" void kernel_launch(void* const* d_in, const int* in_sizes, int n_in,
                              void* d_out, int out_size, void* d_ws, size_t ws_size,
                              hipStream_t stream)
{
  (void)in_sizes; (void)n_in; (void)out_size; (void)ws_size;
  const float* query    = (const float*)d_in[0];
  const float* q_w      = (const float*)d_in[1];
  const float* q_b      = (const float*)d_in[2];
  const float* k_w      = (const float*)d_in[3];
  const float* k_b      = (const float*)d_in[4];
  const float* v_w      = (const float*)d_in[5];
  const float* v_b      = (const float*)d_in[6];
  const float* out_w    = (const float*)d_in[7];
  const float* out_b    = (const float*)d_in[8];
  const float* rel_bias = (const float*)d_in[9];
  const float* grep_w   = (const float*)d_in[10];
  const float* grep_b   = (const float*)d_in[11];
  const float* grep_a   = (const float*)d_in[12];

  char* ws = (char*)d_ws;
  size_t off = 0;
  __bf16* qbf = (__bf16*)(ws + off); off += (size_t)4096 * 1024 * 2;   // query bf16 (TB, E)
  __bf16* wq  = (__bf16*)(ws + off); off += (size_t)1024 * 1024 * 2;
  __bf16* wk  = (__bf16*)(ws + off); off += (size_t)1024 * 1024 * 2;
  __bf16* wv  = (__bf16*)(ws + off); off += (size_t)1024 * 1024 * 2;
  __bf16* wo  = (__bf16*)(ws + off); off += (size_t)1024 * 1024 * 2;
  __bf16* qh  = (__bf16*)(ws + off); off += (size_t)4096 * 1024 * 2;   // (B,H,T,DH)
  __bf16* kh  = (__bf16*)(ws + off); off += (size_t)4096 * 1024 * 2;   // (B,H,T,DH)
  __bf16* vhT = (__bf16*)(ws + off); off += (size_t)4096 * 1024 * 2;   // (B,H,DH,T)
  __bf16* ctx = (__bf16*)(ws + off); off += (size_t)4096 * 1024 * 2;   // (TB, E)
  float* gates = (float*)(ws + off); off += (size_t)65536 * 4;         // (B*H, T), * log2e
  __bf16* tab  = (__bf16*)(ws + off); off += (size_t)16 * 2047 * 2;    // (H, 2047) bf16

  cvt4_kernel<<<dim3(1024, 4), 256, 0, stream>>>(q_w, k_w, v_w, out_w, wq, wk, wv, wo);
  gates_kernel<<<256, 256, 0, stream>>>(query, grep_w, grep_b, grep_a, gates, qbf);
  tab_kernel<<<dim3(8, 16), 256, 0, stream>>>(rel_bias, tab);
  gemm_qkv<<<dim3(8, 32, 3), 256, 0, stream>>>(qbf, wq, wk, wv, q_b, k_b, v_b, qh, kh, vhT);
  attn_kernel<<<1024, 256, 0, stream>>>(qh, kh, vhT, gates, tab, ctx);
  gemm_out<<<dim3(8, 64), 256, 0, stream>>>(ctx, wo, out_b, (float*)d_out);
}

// Round 4
// 226.969 us; speedup vs baseline: 1.1304x; 1.0095x over previous
//
#include <hip/hip_runtime.h>
#include <math.h>

// Problem constants (reference: T,B,E,H = 1024,4,1024,16; DH=64; 32 buckets, max_dist 128)
#define T_ 1024
#define B_ 4
#define E_ 1024
#define H_ 16
#define DH_ 64

#define LOG2E 1.44269504088896f

typedef __attribute__((ext_vector_type(8))) __bf16 bf16x8;
typedef __attribute__((ext_vector_type(4))) __bf16 bf16x4;
typedef __attribute__((ext_vector_type(4))) float f32x4;

// fp32 -> bf16 round-to-nearest-even
__device__ __forceinline__ __bf16 f2bf(float x){
  union { unsigned short u; __bf16 b; } cv;
  unsigned u32 = __float_as_uint(x);
  cv.u = (unsigned short)((u32 + 0x7fffu + ((u32 >> 16) & 1u)) >> 16);
  return cv.b;
}
// fp32 -> bf16 round-half-up (cheaper; used only for P >= 0)
__device__ __forceinline__ __bf16 f2bf_fast(float x){
  union { unsigned short u; __bf16 b; } cv;
  cv.u = (unsigned short)((__float_as_uint(x) + 0x8000u) >> 16);
  return cv.b;
}

// async global->LDS, 16B per lane; LDS dest is wave-uniform base + lane*16 (m97/m104)
__device__ __forceinline__ void glds16(const void* g, void* l){
  __builtin_amdgcn_global_load_lds(
      (__attribute__((address_space(1))) void*)(void*)g,
      (__attribute__((address_space(3))) void*)l,
      16, 0, 0);
}

// ---------------- 4 weight matrices fp32->bf16 in one launch ----------------
__global__ void cvt4_kernel(const float* __restrict__ a0, const float* __restrict__ a1,
                            const float* __restrict__ a2, const float* __restrict__ a3,
                            __bf16* __restrict__ o0, __bf16* __restrict__ o1,
                            __bf16* __restrict__ o2, __bf16* __restrict__ o3){
  const float* a; __bf16* o;
  switch (blockIdx.y){
    case 0: a = a0; o = o0; break;
    case 1: a = a1; o = o1; break;
    case 2: a = a2; o = o2; break;
    default: a = a3; o = o3; break;
  }
  int i = (blockIdx.x * 256 + threadIdx.x) * 4;
  float4 v = *(const float4*)(a + i);
  bf16x4 r;
  r[0] = f2bf(v.x); r[1] = f2bf(v.y); r[2] = f2bf(v.z); r[3] = f2bf(v.w);
  *(bf16x4*)(o + i) = r;
}

// ---------------- gates + query bf16 conversion, fused ----------------
__global__ __launch_bounds__(256) void gates_kernel(
    const float* __restrict__ query, const float* __restrict__ gw,
    const float* __restrict__ gb, const float* __restrict__ ga,
    float* __restrict__ gates, __bf16* __restrict__ qbf){
  int t = blockIdx.x * 4 + (threadIdx.x >> 6);
  int bh = threadIdx.x & 63;
  int h = bh & 15;
  const float* q = query + (size_t)t * E_ * B_ + bh * 64;
  __bf16* qo = qbf + (size_t)t * E_ * B_ + bh * 64;
  float g[8];
  #pragma unroll
  for (int e = 0; e < 8; e++) g[e] = gb[e];
  #pragma unroll
  for (int c = 0; c < 8; c++){
    float4 v0 = *(const float4*)(q + c * 8);
    float4 v1 = *(const float4*)(q + c * 8 + 4);
    bf16x8 o;
    o[0] = f2bf(v0.x); o[1] = f2bf(v0.y); o[2] = f2bf(v0.z); o[3] = f2bf(v0.w);
    o[4] = f2bf(v1.x); o[5] = f2bf(v1.y); o[6] = f2bf(v1.z); o[7] = f2bf(v1.w);
    *(bf16x8*)(qo + c * 8) = o;
    #pragma unroll
    for (int e = 0; e < 8; e++){
      const float* w = gw + e * 64 + c * 8;     // uniform -> s_load
      g[e] += v0.x * w[0] + v0.y * w[1] + v0.z * w[2] + v0.w * w[3]
            + v1.x * w[4] + v1.y * w[5] + v1.z * w[6] + v1.w * w[7];
    }
  }
  float a0 = (g[0] + g[1]) + (g[2] + g[3]);
  float a1 = (g[4] + g[5]) + (g[6] + g[7]);
  float sa = 1.f / (1.f + __expf(-a0));
  float sb = 1.f / (1.f + __expf(-a1));
  gates[bh * T_ + t] = (sa * (sb * ga[h] - 1.0f) + 2.0f) * LOG2E;   // pre-scaled for exp2 softmax
}

// ---------------- relative-position bias table (bf16): tab[h][rp+1023] ----------------
__global__ void tab_kernel(const float* __restrict__ rel_bias, __bf16* __restrict__ tab){
  int i = blockIdx.x * 256 + threadIdx.x;
  if (i >= 2047) return;
  int h = blockIdx.y;
  int rp = i - 1023;
  int base = rp > 0 ? 16 : 0;
  int arp = rp < 0 ? -rp : rp;
  int off;
  if (arp < 8) off = arp;
  else {
    float val = (logf((float)arp * 0.125f) / 2.772588722239781f) * 8.0f;
    int lg = (int)val;
    off = 8 + (lg > 7 ? 7 : lg);
  }
  tab[h * 2047 + i] = f2bf(rel_bias[(base + off) * H_ + h]);
}

// ---------------- QKV GEMM: 128x128 tile, z selects q/k/v ----------------
// z=0/1 (q,k): scatter bf16 to (B,H,T,DH) in 32B granules.
// z=2  (v):   LDS-transpose epilogue -> (B,H,DH,T) in 64B-contiguous per-thread stores.
__global__ __launch_bounds__(256) void gemm_qkv(
    const __bf16* __restrict__ A,
    const __bf16* __restrict__ W0, const __bf16* __restrict__ W1, const __bf16* __restrict__ W2,
    const float* __restrict__ b0, const float* __restrict__ b1, const float* __restrict__ b2,
    __bf16* out0, __bf16* out1, __bf16* out2)
{
  __shared__ __bf16 smem[2][128 * 32];   // As/Bs; re-used as 64x4x32 transpose buffer in v-epilogue
  __bf16* As = smem[0];
  __bf16* Bs = smem[1];
  const int tid = threadIdx.x;
  const int lane = tid & 63, wid = tid >> 6;
  const int l15 = lane & 15, quad = lane >> 4;
  const int wm = wid >> 1, wn = wid & 1;
  const int m0 = blockIdx.y * 128, n0 = blockIdx.x * 128;

  const __bf16* W = W0;
  const float* bias = b0;
  float scale = 1.0f;
  __bf16* outp = out0;
  int z = blockIdx.z;
  if (z == 0){ scale = 0.125f * LOG2E; }               // q: *DH^-0.5 * log2e
  else if (z == 1){ W = W1; bias = b1; outp = out1; }  // k
  else            { W = W2; bias = b2; outp = out2; }  // v

  f32x4 acc[4][4];
  #pragma unroll
  for (int i = 0; i < 4; i++)
    #pragma unroll
    for (int j = 0; j < 4; j++){
      acc[i][j][0] = 0.f; acc[i][j][1] = 0.f; acc[i][j][2] = 0.f; acc[i][j][3] = 0.f;
    }

  const int grow = lane >> 2;
  const int gcol = (lane & 3) * 8;

  for (int k0 = 0; k0 < E_; k0 += 32){
    __syncthreads();
    #pragma unroll
    for (int r2 = 0; r2 < 2; r2++){
      int rb = (wid * 2 + r2) * 16;
      glds16(A + (size_t)(m0 + rb + grow) * E_ + k0 + gcol, &As[rb * 32]);
      glds16(W + (size_t)(n0 + rb + grow) * E_ + k0 + gcol, &Bs[rb * 32]);
    }
    __syncthreads();
    bf16x8 am[4], bn[4];
    #pragma unroll
    for (int i = 0; i < 4; i++) am[i] = *(const bf16x8*)&As[(wm * 64 + i * 16 + l15) * 32 + quad * 8];
    #pragma unroll
    for (int j = 0; j < 4; j++) bn[j] = *(const bf16x8*)&Bs[(wn * 64 + j * 16 + l15) * 32 + quad * 8];
    #pragma unroll
    for (int i = 0; i < 4; i++)
      #pragma unroll
      for (int j = 0; j < 4; j++)
        acc[i][j] = __builtin_amdgcn_mfma_f32_16x16x32_bf16(am[i], bn[j], acc[i][j], 0, 0, 0);
  }

  if (z != 2){
    // q/k epilogue: C/D layout col=lane&15, row=quad*4+reg (m89/m91); 32B-coalesced scatter
    #pragma unroll
    for (int i = 0; i < 4; i++){
      const int row0 = m0 + wm * 64 + i * 16 + quad * 4;
      #pragma unroll
      for (int j = 0; j < 4; j++){
        const int col = n0 + wn * 64 + j * 16 + l15;
        const float bc = bias[col];
        #pragma unroll
        for (int r = 0; r < 4; r++){
          float v = (acc[i][j][r] + bc) * scale;
          int row = row0 + r;
          int t = row >> 2, bb = row & 3;       // m = t*B + b
          int hh = col >> 6, dd = col & 63;     // n = h*DH + d
          outp[(size_t)((bb * H_ + hh) * T_ + t) * DH_ + dd] = f2bf(v);
        }
      }
    }
  } else {
    // v epilogue: transpose via LDS -> (B,H,DH,T); per-thread 64B-contiguous t-runs.
    // vbuf[n_local(64)][bb(4)][t_local(32)] = 8192 bf16 = exactly smem's 16KB.
    __bf16 (*vbuf)[4][32] = (__bf16 (*)[4][32])&smem[0][0];
    const int tb0 = m0 >> 2;                    // t-range base of this tile (32 t's)
    #pragma unroll
    for (int p = 0; p < 2; p++){                // pass p handles n_local in [p*64, p*64+64)
      __syncthreads();
      if (wn == p){
        #pragma unroll
        for (int i = 0; i < 4; i++){
          const int t_local = wm * 16 + i * 4 + quad;
          #pragma unroll
          for (int j = 0; j < 4; j++){
            const int nl = j * 16 + l15;        // within-pass n_local
            const float bc = bias[n0 + p * 64 + nl];
            #pragma unroll
            for (int r = 0; r < 4; r++)
              vbuf[nl][r][t_local] = f2bf(acc[i][j][r] + bc);
          }
        }
      }
      __syncthreads();
      const int nl = tid >> 2;
      const int bb = tid & 3;
      const int colg = n0 + p * 64 + nl;
      const int hh = colg >> 6, dd = colg & 63;
      __bf16* dst = outp + (size_t)((bb * H_ + hh) * DH_ + dd) * T_ + tb0;
      const __bf16* src = &vbuf[nl][bb][0];
      #pragma unroll
      for (int c = 0; c < 2; c++)
        *(bf16x8*)(dst + c * 8 + ((tid & 2) ? 16 : 0) * 0) = *(const bf16x8*)(src + c * 8);
      #pragma unroll
      for (int c = 2; c < 4; c++)
        *(bf16x8*)(dst + c * 8) = *(const bf16x8*)(src + c * 8);
    }
  }
}

// ---------------- out-proj GEMM: 64x128 tile, fp32 write ----------------
__global__ __launch_bounds__(256) void gemm_out(
    const __bf16* __restrict__ A, const __bf16* __restrict__ W,
    const float* __restrict__ bias, float* __restrict__ out)
{
  __shared__ __bf16 As[64 * 32];
  __shared__ __bf16 Bs[128 * 32];
  const int tid = threadIdx.x;
  const int lane = tid & 63, wid = tid >> 6;
  const int l15 = lane & 15, quad = lane >> 4;
  const int wm = wid >> 1, wn = wid & 1;
  const int m0 = blockIdx.y * 64, n0 = blockIdx.x * 128;

  f32x4 acc[2][4];
  #pragma unroll
  for (int i = 0; i < 2; i++)
    #pragma unroll
    for (int j = 0; j < 4; j++){
      acc[i][j][0] = 0.f; acc[i][j][1] = 0.f; acc[i][j][2] = 0.f; acc[i][j][3] = 0.f;
    }

  const int grow = lane >> 2;
  const int gcol = (lane & 3) * 8;

  for (int k0 = 0; k0 < E_; k0 += 32){
    __syncthreads();
    glds16(A + (size_t)(m0 + wid * 16 + grow) * E_ + k0 + gcol, &As[wid * 16 * 32]);
    #pragma unroll
    for (int r2 = 0; r2 < 2; r2++){
      int rb = (wid * 2 + r2) * 16;
      glds16(W + (size_t)(n0 + rb + grow) * E_ + k0 + gcol, &Bs[rb * 32]);
    }
    __syncthreads();
    bf16x8 am[2], bn[4];
    #pragma unroll
    for (int i = 0; i < 2; i++) am[i] = *(const bf16x8*)&As[(wm * 32 + i * 16 + l15) * 32 + quad * 8];
    #pragma unroll
    for (int j = 0; j < 4; j++) bn[j] = *(const bf16x8*)&Bs[(wn * 64 + j * 16 + l15) * 32 + quad * 8];
    #pragma unroll
    for (int i = 0; i < 2; i++)
      #pragma unroll
      for (int j = 0; j < 4; j++)
        acc[i][j] = __builtin_amdgcn_mfma_f32_16x16x32_bf16(am[i], bn[j], acc[i][j], 0, 0, 0);
  }

  #pragma unroll
  for (int i = 0; i < 2; i++){
    const int row0 = m0 + wm * 32 + i * 16 + quad * 4;
    #pragma unroll
    for (int j = 0; j < 4; j++){
      const int col = n0 + wn * 64 + j * 16 + l15;
      const float bc = bias[col];
      #pragma unroll
      for (int r = 0; r < 4; r++)
        out[(size_t)(row0 + r) * E_ + col] = acc[i][j][r] + bc;
    }
  }
}

// ---------------- flash attention v4: 128 t per block, 2 t-groups/wave ----------------
// grid 512; XCD swizzle pins all 8 t-blocks of one bh to one XCD (K/V L2-resident).
// K/V LDS frag reads are shared across both t-groups: 20 b128 reads per 32 MFMAs.
__global__ __launch_bounds__(256) void attn_kernel(
    const __bf16* __restrict__ qg, const __bf16* __restrict__ kg, const __bf16* __restrict__ vgT,
    const float* __restrict__ gates, const __bf16* __restrict__ tab,
    __bf16* __restrict__ ctx)
{
  const int LD = 72;                   // 144B rows
  __shared__ __bf16 Ks[64 * LD];       // K-tile (s, d)
  __shared__ __bf16 Vt[64 * LD];       // V^T tile (d, s)
  __shared__ __bf16 Pt[4][2][16 * LD]; // per-wave, per-t-group P^T — wave-local, no barrier
  __shared__ __bf16 tabh[2048];

  const int tid = threadIdx.x;
  const int lane = tid & 63, wid = tid >> 6;
  const int l15 = lane & 15, quad = lane >> 4;
  // XCD swizzle: all 8 blocks of a bh share d%8
  const int dgrid = blockIdx.x;
  const int jj = dgrid >> 3;
  const int bh = (dgrid & 7) + 8 * (jj & 7);
  const int tq = jj >> 3;              // 0..7 -> t-base tq*128
  const int b = bh >> 4, h = bh & 15;
  const __bf16* qb = qg + (size_t)bh * T_ * DH_;
  const __bf16* kb = kg + (size_t)bh * T_ * DH_;
  const __bf16* vb = vgT + (size_t)bh * DH_ * T_;

  for (int i = tid; i < 2047; i += 256) tabh[i] = tab[h * 2047 + i];

  const int t0w = tq * 128 + wid * 32; // wave owns 32 t = 2 groups of 16
  bf16x8 bq[2][2];
  float g[2];
  int ibase[2];
  #pragma unroll
  for (int tg = 0; tg < 2; tg++){
    int t_lane = t0w + tg * 16 + l15;
    bq[tg][0] = *(const bf16x8*)(qb + (size_t)t_lane * DH_ + quad * 8);
    bq[tg][1] = *(const bf16x8*)(qb + (size_t)t_lane * DH_ + 32 + quad * 8);
    g[tg] = gates[bh * T_ + t_lane];   // already * log2e
    ibase[tg] = 1023 - t_lane;
  }

  // staging: thread covers rows r0, r0+32 of both Ks and Vt (4 b128 per thread)
  const int r0 = tid >> 3;
  const int c0 = (tid & 7) * 8;

  float l_run[2] = {0.f, 0.f};
  f32x4 O[2][4];
  #pragma unroll
  for (int tg = 0; tg < 2; tg++)
    #pragma unroll
    for (int mt = 0; mt < 4; mt++){ O[tg][mt][0]=0.f; O[tg][mt][1]=0.f; O[tg][mt][2]=0.f; O[tg][mt][3]=0.f; }

  // prefetch tile 0
  bf16x8 kA = *(const bf16x8*)(kb + (size_t)r0 * DH_ + c0);
  bf16x8 kB = *(const bf16x8*)(kb + (size_t)(r0 + 32) * DH_ + c0);
  bf16x8 vA = *(const bf16x8*)(vb + (size_t)r0 * T_ + c0);
  bf16x8 vB = *(const bf16x8*)(vb + (size_t)(r0 + 32) * T_ + c0);

  for (int s0 = 0; s0 < T_; s0 += 64){
    __syncthreads();
    *(bf16x8*)&Ks[r0 * LD + c0] = kA;
    *(bf16x8*)&Ks[(r0 + 32) * LD + c0] = kB;
    *(bf16x8*)&Vt[r0 * LD + c0] = vA;
    *(bf16x8*)&Vt[(r0 + 32) * LD + c0] = vB;
    __syncthreads();

    // prefetch next tile (wraps; discarded at tail) — overlaps compute
    int sn = (s0 + 64) & (T_ - 1);
    kA = *(const bf16x8*)(kb + (size_t)(sn + r0) * DH_ + c0);
    kB = *(const bf16x8*)(kb + (size_t)(sn + r0 + 32) * DH_ + c0);
    vA = *(const bf16x8*)(vb + (size_t)r0 * T_ + sn + c0);
    vB = *(const bf16x8*)(vb + (size_t)(r0 + 32) * T_ + sn + c0);

    // S^T = K.Q^T: A=K (shared across tg), B=Q^T. D: S^T[s=nt*16+quad*4+r][t=l15]
    f32x4 S[2][4];
    #pragma unroll
    for (int nt = 0; nt < 4; nt++){
      bf16x8 ak0 = *(const bf16x8*)&Ks[(nt * 16 + l15) * LD + quad * 8];
      bf16x8 ak1 = *(const bf16x8*)&Ks[(nt * 16 + l15) * LD + 32 + quad * 8];
      #pragma unroll
      for (int tg = 0; tg < 2; tg++){
        f32x4 a; a[0]=0.f; a[1]=0.f; a[2]=0.f; a[3]=0.f;
        a = __builtin_amdgcn_mfma_f32_16x16x32_bf16(ak0, bq[tg][0], a, 0, 0, 0);
        a = __builtin_amdgcn_mfma_f32_16x16x32_bf16(ak1, bq[tg][1], a, 0, 0, 0);
        S[tg][nt] = a;
      }
    }

    // bias + exp2 (no max-shift: scores O(10), fp32 exp2 safe; softmax shift-invariant)
    #pragma unroll
    for (int tg = 0; tg < 2; tg++){
      const int ib = ibase[tg] + s0;
      #pragma unroll
      for (int nt = 0; nt < 4; nt++)
        #pragma unroll
        for (int r = 0; r < 4; r++)
          S[tg][nt][r] = __builtin_amdgcn_exp2f(S[tg][nt][r] + g[tg] * (float)tabh[ib + nt * 16 + quad * 4 + r]);

      // P^T -> wave-local LDS (t-major), b64 writes
      __bf16* pw = &Pt[wid][tg][0];
      #pragma unroll
      for (int nt = 0; nt < 4; nt++){
        bf16x4 p;
        p[0] = f2bf_fast(S[tg][nt][0]); p[1] = f2bf_fast(S[tg][nt][1]);
        p[2] = f2bf_fast(S[tg][nt][2]); p[3] = f2bf_fast(S[tg][nt][3]);
        *(bf16x4*)&pw[l15 * LD + nt * 16 + quad * 4] = p;
      }

      // denominator (off critical path)
      float rs = 0.f;
      #pragma unroll
      for (int nt = 0; nt < 4; nt++) rs += (S[tg][nt][0] + S[tg][nt][1]) + (S[tg][nt][2] + S[tg][nt][3]);
      rs += __shfl_xor(rs, 16, 64);
      rs += __shfl_xor(rs, 32, 64);
      l_run[tg] += rs;
    }

    // O^T += V^T.P^T: A=V^T (shared across tg), B=P^T
    #pragma unroll
    for (int ks = 0; ks < 2; ks++){
      bf16x8 bp[2];
      #pragma unroll
      for (int tg = 0; tg < 2; tg++)
        bp[tg] = *(const bf16x8*)&Pt[wid][tg][l15 * LD + ks * 32 + quad * 8];
      #pragma unroll
      for (int mt = 0; mt < 4; mt++){
        bf16x8 av = *(const bf16x8*)&Vt[(mt * 16 + l15) * LD + ks * 32 + quad * 8];
        #pragma unroll
        for (int tg = 0; tg < 2; tg++)
          O[tg][mt] = __builtin_amdgcn_mfma_f32_16x16x32_bf16(av, bp[tg], O[tg][mt], 0, 0, 0);
      }
    }
  }

  // epilogue: ctx[(t*B+b)*E + h*64+d], d = mt*16+quad*4+r
  #pragma unroll
  for (int tg = 0; tg < 2; tg++){
    const int t_lane = t0w + tg * 16 + l15;
    const float inv = 1.f / l_run[tg];
    #pragma unroll
    for (int mt = 0; mt < 4; mt++){
      bf16x4 o;
      o[0] = f2bf(O[tg][mt][0] * inv); o[1] = f2bf(O[tg][mt][1] * inv);
      o[2] = f2bf(O[tg][mt][2] * inv); o[3] = f2bf(O[tg][mt][3] * inv);
      *(bf16x4*)&ctx[(size_t)(t_lane * B_ + b) * E_ + h * DH_ + mt * 16 + quad * 4] = o;
    }
  }
}

extern "C" void kernel_launch(void* const* d_in, const int* in_sizes, int n_in,
                              void* d_out, int out_size, void* d_ws, size_t ws_size,
                              hipStream_t stream)
{
  (void)in_sizes; (void)n_in; (void)out_size; (void)ws_size;
  const float* query    = (const float*)d_in[0];
  const float* q_w      = (const float*)d_in[1];
  const float* q_b      = (const float*)d_in[2];
  const float* k_w      = (const float*)d_in[3];
  const float* k_b      = (const float*)d_in[4];
  const float* v_w      = (const float*)d_in[5];
  const float* v_b      = (const float*)d_in[6];
  const float* out_w    = (const float*)d_in[7];
  const float* out_b    = (const float*)d_in[8];
  const float* rel_bias = (const float*)d_in[9];
  const float* grep_w   = (const float*)d_in[10];
  const float* grep_b   = (const float*)d_in[11];
  const float* grep_a   = (const float*)d_in[12];

  char* ws = (char*)d_ws;
  size_t off = 0;
  __bf16* qbf = (__bf16*)(ws + off); off += (size_t)4096 * 1024 * 2;   // query bf16 (TB, E)
  __bf16* wq  = (__bf16*)(ws + off); off += (size_t)1024 * 1024 * 2;
  __bf16* wk  = (__bf16*)(ws + off); off += (size_t)1024 * 1024 * 2;
  __bf16* wv  = (__bf16*)(ws + off); off += (size_t)1024 * 1024 * 2;
  __bf16* wo  = (__bf16*)(ws + off); off += (size_t)1024 * 1024 * 2;
  __bf16* qh  = (__bf16*)(ws + off); off += (size_t)4096 * 1024 * 2;   // (B,H,T,DH)
  __bf16* kh  = (__bf16*)(ws + off); off += (size_t)4096 * 1024 * 2;   // (B,H,T,DH)
  __bf16* vhT = (__bf16*)(ws + off); off += (size_t)4096 * 1024 * 2;   // (B,H,DH,T)
  __bf16* ctx = (__bf16*)(ws + off); off += (size_t)4096 * 1024 * 2;   // (TB, E)
  float* gates = (float*)(ws + off); off += (size_t)65536 * 4;         // (B*H, T), * log2e
  __bf16* tab  = (__bf16*)(ws + off); off += (size_t)16 * 2047 * 2;    // (H, 2047) bf16

  cvt4_kernel<<<dim3(1024, 4), 256, 0, stream>>>(q_w, k_w, v_w, out_w, wq, wk, wv, wo);
  gates_kernel<<<256, 256, 0, stream>>>(query, grep_w, grep_b, grep_a, gates, qbf);
  tab_kernel<<<dim3(8, 16), 256, 0, stream>>>(rel_bias, tab);
  gemm_qkv<<<dim3(8, 32, 3), 256, 0, stream>>>(qbf, wq, wk, wv, q_b, k_b, v_b, qh, kh, vhT);
  attn_kernel<<<512, 256, 0, stream>>>(qh, kh, vhT, gates, tab, ctx);
  gemm_out<<<dim3(8, 64), 256, 0, stream>>>(ctx, wo, out_b, (float*)d_out);
}